// Round 1
// baseline (9557.541 us; speedup 1.0000x reference)
//
#include <hip/hip_runtime.h>
#include <hip/hip_bf16.h>
#include <math.h>

#define BATCH   2
#define SLEN    2048
#define DMODEL  4096
#define NHEADS  32
#define KVHEADS 8
#define HD      128
#define KVDIM   (KVHEADS*HD)   // 1024
#define MROWS   (BATCH*SLEN)   // 4096

// ---------------- RoPE tables: cos/sin [SLEN][64] ----------------
__global__ void rope_table_k(const int* __restrict__ pos,
                             float* __restrict__ cosT, float* __restrict__ sinT) {
    int s = blockIdx.x;
    int d = threadIdx.x;          // 0..63
    float p = (float)pos[s];
    float inv = powf(10000.0f, -(float)(2 * d) / 128.0f);
    float ang = p * inv;
    cosT[s * 64 + d] = cosf(ang);
    sinT[s * 64 + d] = sinf(ang);
}

// ---------------- RoPE apply in-place on [M, nh*128] ----------------
__global__ void rope_apply_k(float* __restrict__ x, const float* __restrict__ cosT,
                             const float* __restrict__ sinT, int nh) {
    int idx = blockIdx.x * 256 + threadIdx.x;   // one thread per (row, h, pair)
    int d = idx & 63;
    int rest = idx >> 6;
    int h = rest % nh;
    int row = rest / nh;                        // b*SLEN + s
    int s = row & (SLEN - 1);
    float c  = cosT[s * 64 + d];
    float sn = sinT[s * 64 + d];
    float* base = x + (size_t)row * (nh * HD) + h * HD;
    float x1 = base[d], x2 = base[d + 64];
    base[d]      = x1 * c - x2 * sn;
    base[d + 64] = x2 * c + x1 * sn;
}

// ---------------- GEMM-NT: C[M,N] = A[M,K] * W[N,K]^T (fp32 baseline) ----------------
// 64x64 tile, BK=16, 256 threads, 4x4 register micro-tile per thread.
__global__ __launch_bounds__(256) void gemm_nt_k(
    const float* __restrict__ A, const float* __restrict__ W,
    float* __restrict__ C, int M, int N, int K) {
    __shared__ float As[16][65];
    __shared__ float Ws[16][65];
    const int t  = threadIdx.x;
    const int m0 = blockIdx.y * 64;
    const int n0 = blockIdx.x * 64;
    const int tx = t & 15, ty = t >> 4;
    const int lrow = t >> 2;          // 0..63
    const int lk   = (t & 3) << 2;    // 0,4,8,12
    float acc[4][4] = {};
    for (int k0 = 0; k0 < K; k0 += 16) {
        float4 av = *(const float4*)(A + (size_t)(m0 + lrow) * K + k0 + lk);
        float4 wv = *(const float4*)(W + (size_t)(n0 + lrow) * K + k0 + lk);
        __syncthreads();
        As[lk+0][lrow] = av.x; As[lk+1][lrow] = av.y; As[lk+2][lrow] = av.z; As[lk+3][lrow] = av.w;
        Ws[lk+0][lrow] = wv.x; Ws[lk+1][lrow] = wv.y; Ws[lk+2][lrow] = wv.z; Ws[lk+3][lrow] = wv.w;
        __syncthreads();
        #pragma unroll
        for (int kk = 0; kk < 16; ++kk) {
            float a[4], b[4];
            #pragma unroll
            for (int i = 0; i < 4; ++i) a[i] = As[kk][ty * 4 + i];
            #pragma unroll
            for (int j = 0; j < 4; ++j) b[j] = Ws[kk][tx * 4 + j];
            #pragma unroll
            for (int i = 0; i < 4; ++i)
                #pragma unroll
                for (int j = 0; j < 4; ++j)
                    acc[i][j] = fmaf(a[i], b[j], acc[i][j]);
        }
    }
    #pragma unroll
    for (int i = 0; i < 4; ++i)
        #pragma unroll
        for (int j = 0; j < 4; ++j)
            C[(size_t)(m0 + ty * 4 + i) * N + n0 + tx * 4 + j] = acc[i][j];
}

// ---------------- Flash attention fp32, causal, GQA ----------------
// grid: (SLEN/64, BATCH*NHEADS). 256 threads. QB=KB=64.
// Q layout [B*S, 32*128]; K/V layout [B*S, 8*128]. Output written over Q buffer.
__global__ __launch_bounds__(256) void flash_k(
    const float* __restrict__ Q, const float* __restrict__ Kb,
    const float* __restrict__ Vb, float* __restrict__ O) {
    __shared__ float Qs[64][132];
    __shared__ float Ks[64][132];
    __shared__ float Vs[64][132];
    __shared__ float Ps[64][68];
    const int t  = threadIdx.x;
    const int qt = blockIdx.x;
    const int bh = blockIdx.y;
    const int b  = bh >> 5;
    const int h  = bh & 31;
    const int kvh = h >> 2;          // groups = 4
    const int q0 = qt * 64;
    const size_t qrowBase = (size_t)b * SLEN + q0;

    // stage Q tile (stays resident)
    for (int i = t; i < 64 * 32; i += 256) {
        int r = i >> 5, c4 = (i & 31) << 2;
        *(float4*)&Qs[r][c4] = *(const float4*)(Q + (qrowBase + r) * DMODEL + h * HD + c4);
    }

    const int g  = t >> 4;           // row group 0..15 (within one wave)
    const int tx = t & 15;
    const int tq = g * 4;            // rows tq..tq+3
    const int d0 = tx * 8;           // output d-slice

    float m_i[4], l_i[4], Oacc[4][8];
    #pragma unroll
    for (int i = 0; i < 4; ++i) {
        m_i[i] = -INFINITY; l_i[i] = 0.f;
        #pragma unroll
        for (int dd = 0; dd < 8; ++dd) Oacc[i][dd] = 0.f;
    }
    const float scale = 0.088388347648318447f;   // 1/sqrt(128)

    for (int kt = 0; kt <= qt; ++kt) {
        __syncthreads();   // previous iteration done with Ks/Vs
        const size_t krowBase = (size_t)b * SLEN + kt * 64;
        for (int i = t; i < 64 * 32; i += 256) {
            int r = i >> 5, c4 = (i & 31) << 2;
            *(float4*)&Ks[r][c4] = *(const float4*)(Kb + (krowBase + r) * KVDIM + kvh * HD + c4);
            *(float4*)&Vs[r][c4] = *(const float4*)(Vb + (krowBase + r) * KVDIM + kvh * HD + c4);
        }
        __syncthreads();

        // scores: rows tq..tq+3, cols tx+16j (j=0..3)
        float sc[4][4] = {};
        for (int d = 0; d < HD; ++d) {
            float a[4], bb[4];
            #pragma unroll
            for (int i = 0; i < 4; ++i) a[i] = Qs[tq + i][d];
            #pragma unroll
            for (int j = 0; j < 4; ++j) bb[j] = Ks[tx + 16 * j][d];
            #pragma unroll
            for (int i = 0; i < 4; ++i)
                #pragma unroll
                for (int j = 0; j < 4; ++j)
                    sc[i][j] = fmaf(a[i], bb[j], sc[i][j]);
        }

        // causal mask + scale + row max
        float pmax[4];
        #pragma unroll
        for (int i = 0; i < 4; ++i) {
            int qi = q0 + tq + i;
            #pragma unroll
            for (int j = 0; j < 4; ++j) {
                int ki = kt * 64 + tx + 16 * j;
                sc[i][j] = (ki <= qi) ? sc[i][j] * scale : -INFINITY;
            }
            pmax[i] = fmaxf(fmaxf(sc[i][0], sc[i][1]), fmaxf(sc[i][2], sc[i][3]));
        }
        #pragma unroll
        for (int m = 1; m < 16; m <<= 1)
            #pragma unroll
            for (int i = 0; i < 4; ++i)
                pmax[i] = fmaxf(pmax[i], __shfl_xor(pmax[i], m, 16));

        float alpha[4], rsum[4];
        #pragma unroll
        for (int i = 0; i < 4; ++i) {
            float mn = fmaxf(m_i[i], pmax[i]);
            alpha[i] = expf(m_i[i] - mn);
            m_i[i] = mn;
            float s = 0.f;
            #pragma unroll
            for (int j = 0; j < 4; ++j) {
                float p = expf(sc[i][j] - mn);   // -inf -> 0
                sc[i][j] = p; s += p;
            }
            rsum[i] = s;
        }
        #pragma unroll
        for (int m = 1; m < 16; m <<= 1)
            #pragma unroll
            for (int i = 0; i < 4; ++i)
                rsum[i] += __shfl_xor(rsum[i], m, 16);
        #pragma unroll
        for (int i = 0; i < 4; ++i) {
            l_i[i] = l_i[i] * alpha[i] + rsum[i];
            #pragma unroll
            for (int dd = 0; dd < 8; ++dd) Oacc[i][dd] *= alpha[i];
        }

        // share P within the wave's row-group (same-wave write->read, no barrier needed)
        #pragma unroll
        for (int i = 0; i < 4; ++i)
            #pragma unroll
            for (int j = 0; j < 4; ++j)
                Ps[tq + i][tx + 16 * j] = sc[i][j];

        // PV: O[tq+i][d0..d0+7] += sum_kk P[tq+i][kk] * V[kk][d]
        for (int kk = 0; kk < 64; ++kk) {
            float4 v0 = *(const float4*)&Vs[kk][d0];
            float4 v1 = *(const float4*)&Vs[kk][d0 + 4];
            #pragma unroll
            for (int i = 0; i < 4; ++i) {
                float p = Ps[tq + i][kk];
                Oacc[i][0] = fmaf(p, v0.x, Oacc[i][0]);
                Oacc[i][1] = fmaf(p, v0.y, Oacc[i][1]);
                Oacc[i][2] = fmaf(p, v0.z, Oacc[i][2]);
                Oacc[i][3] = fmaf(p, v0.w, Oacc[i][3]);
                Oacc[i][4] = fmaf(p, v1.x, Oacc[i][4]);
                Oacc[i][5] = fmaf(p, v1.y, Oacc[i][5]);
                Oacc[i][6] = fmaf(p, v1.z, Oacc[i][6]);
                Oacc[i][7] = fmaf(p, v1.w, Oacc[i][7]);
            }
        }
    }

    // epilogue: normalize and store (over Q buffer region — disjoint per block)
    #pragma unroll
    for (int i = 0; i < 4; ++i) {
        float inv = 1.0f / l_i[i];
        #pragma unroll
        for (int dd = 0; dd < 8; ++dd) {
            O[(qrowBase + tq + i) * DMODEL + h * HD + d0 + dd] = Oacc[i][dd] * inv;
        }
    }
}

extern "C" void kernel_launch(void* const* d_in, const int* in_sizes, int n_in,
                              void* d_out, int out_size, void* d_ws, size_t ws_size,
                              hipStream_t stream) {
    const float* hs  = (const float*)d_in[0];
    const int*   pos = (const int*)d_in[1];
    const float* wq  = (const float*)d_in[2];
    const float* wk  = (const float*)d_in[3];
    const float* wv  = (const float*)d_in[4];
    const float* wo  = (const float*)d_in[5];
    float* out = (float*)d_out;

    char* ws = (char*)d_ws;
    float* Qb   = (float*)(ws);                              // 64 MB  [4096, 4096]
    float* Kb   = (float*)(ws + ((size_t)64 << 20));         // 16 MB  [4096, 1024]
    float* Vb   = (float*)(ws + ((size_t)80 << 20));         // 16 MB  [4096, 1024]
    float* cosT = (float*)(ws + ((size_t)96 << 20));         // 512 KB [2048, 64]
    float* sinT = (float*)(ws + ((size_t)96 << 20) + (size_t)SLEN * 64 * sizeof(float));

    rope_table_k<<<SLEN, 64, 0, stream>>>(pos, cosT, sinT);

    dim3 blk(256);
    gemm_nt_k<<<dim3(DMODEL/64, MROWS/64), blk, 0, stream>>>(hs, wq, Qb, MROWS, DMODEL, DMODEL);
    gemm_nt_k<<<dim3(KVDIM/64,  MROWS/64), blk, 0, stream>>>(hs, wk, Kb, MROWS, KVDIM, DMODEL);
    gemm_nt_k<<<dim3(KVDIM/64,  MROWS/64), blk, 0, stream>>>(hs, wv, Vb, MROWS, KVDIM, DMODEL);

    rope_apply_k<<<(MROWS * NHEADS  * 64) / 256, 256, 0, stream>>>(Qb, cosT, sinT, NHEADS);
    rope_apply_k<<<(MROWS * KVHEADS * 64) / 256, 256, 0, stream>>>(Kb, cosT, sinT, KVHEADS);

    flash_k<<<dim3(SLEN/64, BATCH*NHEADS), blk, 0, stream>>>(Qb, Kb, Vb, Qb);

    gemm_nt_k<<<dim3(DMODEL/64, MROWS/64), blk, 0, stream>>>(Qb, wo, out, MROWS, DMODEL, DMODEL);
}

// Round 2
// 3666.626 us; speedup vs baseline: 2.6066x; 2.6066x over previous
//
#include <hip/hip_runtime.h>
#include <hip/hip_bf16.h>
#include <math.h>

typedef __attribute__((ext_vector_type(8))) short short8;
typedef __attribute__((ext_vector_type(4))) float f32x4;

#define BATCH   2
#define SLEN    2048
#define DMODEL  4096
#define NHEADS  32
#define KVHEADS 8
#define HD      128
#define KVDIM   (KVHEADS*HD)   // 1024
#define MROWS   (BATCH*SLEN)   // 4096

// async global->LDS, 16B per lane, dest = wave-uniform base + lane*16
#define GLDS16(gp, lp) __builtin_amdgcn_global_load_lds( \
    (const __attribute__((address_space(1))) void*)(gp), \
    (__attribute__((address_space(3))) void*)(lp), 16, 0, 0)

// ---------------- fp32 -> bf16 cast (memory-bound, 4 elems/thread) ----------------
__global__ __launch_bounds__(256) void cast_k(const float* __restrict__ in,
                                              unsigned short* __restrict__ out, long n) {
    long i = ((long)blockIdx.x * 256 + threadIdx.x) * 4;
    if (i >= n) return;
    float4 v = *(const float4*)(in + i);
    union { __hip_bfloat16 h[4]; uint2 u; } c;
    c.h[0] = __float2bfloat16(v.x); c.h[1] = __float2bfloat16(v.y);
    c.h[2] = __float2bfloat16(v.z); c.h[3] = __float2bfloat16(v.w);
    *(uint2*)(out + i) = c.u;
}

// ---------------- RoPE tables: cos/sin [SLEN][64] ----------------
__global__ void rope_table_k(const int* __restrict__ pos,
                             float* __restrict__ cosT, float* __restrict__ sinT) {
    int s = blockIdx.x;
    int d = threadIdx.x;          // 0..63
    float p = (float)pos[s];
    float inv = powf(10000.0f, -(float)(2 * d) / 128.0f);
    float ang = p * inv;
    cosT[s * 64 + d] = cosf(ang);
    sinT[s * 64 + d] = sinf(ang);
}

// ---------------- RoPE apply in-place on [M, nh*128] fp32 ----------------
__global__ void rope_apply_k(float* __restrict__ x, const float* __restrict__ cosT,
                             const float* __restrict__ sinT, int nh) {
    int idx = blockIdx.x * 256 + threadIdx.x;
    int d = idx & 63;
    int rest = idx >> 6;
    int h = rest % nh;
    int row = rest / nh;
    int s = row & (SLEN - 1);
    float c  = cosT[s * 64 + d];
    float sn = sinT[s * 64 + d];
    float* base = x + (size_t)row * (nh * HD) + h * HD;
    float x1 = base[d], x2 = base[d + 64];
    base[d]      = x1 * c - x2 * sn;
    base[d + 64] = x2 * c + x1 * sn;
}

// ---------------- bf16 MFMA GEMM-NT: C[M,N] = A[M,K] * W[N,K]^T ----------------
// m97 structure: 128x128 tile, BK=32, 4 waves (2x2 of 64x64), 16 MFMA/K-step,
// global_load_lds width=16 staging, 2 barriers per K-step. fp32 output.
__global__ __launch_bounds__(256) void gemm_bf16_nt(
    const unsigned short* __restrict__ A,   // [M][K] bf16 bits
    const unsigned short* __restrict__ W,   // [N][K] bf16 bits
    float* __restrict__ C,                  // [M][N] fp32
    int M, int N, int K)
{
    __shared__ unsigned short As[128 * 32];   // row-major [128][32], 8KB
    __shared__ unsigned short Bs[128 * 32];
    const int t    = threadIdx.x;
    const int wid  = t >> 6;
    const int lane = t & 63;
    const int m0 = blockIdx.y * 128, n0 = blockIdx.x * 128;
    const int wm = (wid >> 1) * 64, wn = (wid & 1) * 64;

    f32x4 acc[4][4];
    #pragma unroll
    for (int i = 0; i < 4; ++i)
        #pragma unroll
        for (int j = 0; j < 4; ++j)
            acc[i][j] = (f32x4){0.f, 0.f, 0.f, 0.f};

    // staging: wave w, iter it in {0,1}: rows it*64 + w*16 + (lane>>2), k = (lane&3)*8
    const int srow  = wid * 16 + (lane >> 2);
    const int skcol = (lane & 3) * 8;
    const unsigned short* Abase = A + (size_t)(m0 + srow) * K + skcol;
    const unsigned short* Wbase = W + (size_t)(n0 + srow) * K + skcol;
    unsigned short* AsB = As + wid * 512;   // wave-uniform LDS base (elements)
    unsigned short* BsB = Bs + wid * 512;

    // fragment read: lane reads row (lane&15), k-slice (lane>>4)*8  (ds_read_b128)
    const int frow = lane & 15;
    const int fk   = (lane >> 4) * 8;

    for (int k0 = 0; k0 < K; k0 += 32) {
        __syncthreads();   // all waves done reading LDS from previous K-step
        GLDS16(Abase + k0,                   AsB);
        GLDS16(Abase + (size_t)64 * K + k0,  AsB + 2048);
        GLDS16(Wbase + k0,                   BsB);
        GLDS16(Wbase + (size_t)64 * K + k0,  BsB + 2048);
        __syncthreads();   // drains vmcnt(0): staged tile visible

        short8 af[4], bfv[4];
        #pragma unroll
        for (int i = 0; i < 4; ++i)
            af[i] = *(const short8*)&As[(wm + i * 16 + frow) * 32 + fk];
        #pragma unroll
        for (int j = 0; j < 4; ++j)
            bfv[j] = *(const short8*)&Bs[(wn + j * 16 + frow) * 32 + fk];
        #pragma unroll
        for (int i = 0; i < 4; ++i)
            #pragma unroll
            for (int j = 0; j < 4; ++j)
                acc[i][j] = __builtin_amdgcn_mfma_f32_16x16x32_bf16(af[i], bfv[j], acc[i][j], 0, 0, 0);
    }

    // C/D layout (verified m89): col = lane&15, row = (lane>>4)*4 + reg
    const int crow = (lane >> 4) * 4, ccol = lane & 15;
    #pragma unroll
    for (int i = 0; i < 4; ++i)
        #pragma unroll
        for (int j = 0; j < 4; ++j) {
            float* cp = C + (size_t)(m0 + wm + i * 16 + crow) * N + (n0 + wn + j * 16 + ccol);
            #pragma unroll
            for (int r = 0; r < 4; ++r) cp[(size_t)r * N] = acc[i][j][r];
        }
}

// ---------------- Flash attention fp32, causal, GQA (unchanged) ----------------
__global__ __launch_bounds__(256) void flash_k(
    const float* __restrict__ Q, const float* __restrict__ Kb,
    const float* __restrict__ Vb, float* __restrict__ O) {
    __shared__ float Qs[64][132];
    __shared__ float Ks[64][132];
    __shared__ float Vs[64][132];
    __shared__ float Ps[64][68];
    const int t  = threadIdx.x;
    const int qt = blockIdx.x;
    const int bh = blockIdx.y;
    const int b  = bh >> 5;
    const int h  = bh & 31;
    const int kvh = h >> 2;
    const int q0 = qt * 64;
    const size_t qrowBase = (size_t)b * SLEN + q0;

    for (int i = t; i < 64 * 32; i += 256) {
        int r = i >> 5, c4 = (i & 31) << 2;
        *(float4*)&Qs[r][c4] = *(const float4*)(Q + (qrowBase + r) * DMODEL + h * HD + c4);
    }

    const int g  = t >> 4;
    const int tx = t & 15;
    const int tq = g * 4;
    const int d0 = tx * 8;

    float m_i[4], l_i[4], Oacc[4][8];
    #pragma unroll
    for (int i = 0; i < 4; ++i) {
        m_i[i] = -INFINITY; l_i[i] = 0.f;
        #pragma unroll
        for (int dd = 0; dd < 8; ++dd) Oacc[i][dd] = 0.f;
    }
    const float scale = 0.088388347648318447f;

    for (int kt = 0; kt <= qt; ++kt) {
        __syncthreads();
        const size_t krowBase = (size_t)b * SLEN + kt * 64;
        for (int i = t; i < 64 * 32; i += 256) {
            int r = i >> 5, c4 = (i & 31) << 2;
            *(float4*)&Ks[r][c4] = *(const float4*)(Kb + (krowBase + r) * KVDIM + kvh * HD + c4);
            *(float4*)&Vs[r][c4] = *(const float4*)(Vb + (krowBase + r) * KVDIM + kvh * HD + c4);
        }
        __syncthreads();

        float sc[4][4] = {};
        for (int d = 0; d < HD; ++d) {
            float a[4], bb[4];
            #pragma unroll
            for (int i = 0; i < 4; ++i) a[i] = Qs[tq + i][d];
            #pragma unroll
            for (int j = 0; j < 4; ++j) bb[j] = Ks[tx + 16 * j][d];
            #pragma unroll
            for (int i = 0; i < 4; ++i)
                #pragma unroll
                for (int j = 0; j < 4; ++j)
                    sc[i][j] = fmaf(a[i], bb[j], sc[i][j]);
        }

        float pmax[4];
        #pragma unroll
        for (int i = 0; i < 4; ++i) {
            int qi = q0 + tq + i;
            #pragma unroll
            for (int j = 0; j < 4; ++j) {
                int ki = kt * 64 + tx + 16 * j;
                sc[i][j] = (ki <= qi) ? sc[i][j] * scale : -INFINITY;
            }
            pmax[i] = fmaxf(fmaxf(sc[i][0], sc[i][1]), fmaxf(sc[i][2], sc[i][3]));
        }
        #pragma unroll
        for (int m = 1; m < 16; m <<= 1)
            #pragma unroll
            for (int i = 0; i < 4; ++i)
                pmax[i] = fmaxf(pmax[i], __shfl_xor(pmax[i], m, 16));

        float alpha[4], rsum[4];
        #pragma unroll
        for (int i = 0; i < 4; ++i) {
            float mn = fmaxf(m_i[i], pmax[i]);
            alpha[i] = expf(m_i[i] - mn);
            m_i[i] = mn;
            float s = 0.f;
            #pragma unroll
            for (int j = 0; j < 4; ++j) {
                float p = expf(sc[i][j] - mn);
                sc[i][j] = p; s += p;
            }
            rsum[i] = s;
        }
        #pragma unroll
        for (int m = 1; m < 16; m <<= 1)
            #pragma unroll
            for (int i = 0; i < 4; ++i)
                rsum[i] += __shfl_xor(rsum[i], m, 16);
        #pragma unroll
        for (int i = 0; i < 4; ++i) {
            l_i[i] = l_i[i] * alpha[i] + rsum[i];
            #pragma unroll
            for (int dd = 0; dd < 8; ++dd) Oacc[i][dd] *= alpha[i];
        }

        #pragma unroll
        for (int i = 0; i < 4; ++i)
            #pragma unroll
            for (int j = 0; j < 4; ++j)
                Ps[tq + i][tx + 16 * j] = sc[i][j];

        for (int kk = 0; kk < 64; ++kk) {
            float4 v0 = *(const float4*)&Vs[kk][d0];
            float4 v1 = *(const float4*)&Vs[kk][d0 + 4];
            #pragma unroll
            for (int i = 0; i < 4; ++i) {
                float p = Ps[tq + i][kk];
                Oacc[i][0] = fmaf(p, v0.x, Oacc[i][0]);
                Oacc[i][1] = fmaf(p, v0.y, Oacc[i][1]);
                Oacc[i][2] = fmaf(p, v0.z, Oacc[i][2]);
                Oacc[i][3] = fmaf(p, v0.w, Oacc[i][3]);
                Oacc[i][4] = fmaf(p, v1.x, Oacc[i][4]);
                Oacc[i][5] = fmaf(p, v1.y, Oacc[i][5]);
                Oacc[i][6] = fmaf(p, v1.z, Oacc[i][6]);
                Oacc[i][7] = fmaf(p, v1.w, Oacc[i][7]);
            }
        }
    }

    #pragma unroll
    for (int i = 0; i < 4; ++i) {
        float inv = 1.0f / l_i[i];
        #pragma unroll
        for (int dd = 0; dd < 8; ++dd) {
            O[(qrowBase + tq + i) * DMODEL + h * HD + d0 + dd] = Oacc[i][dd] * inv;
        }
    }
}

extern "C" void kernel_launch(void* const* d_in, const int* in_sizes, int n_in,
                              void* d_out, int out_size, void* d_ws, size_t ws_size,
                              hipStream_t stream) {
    const float* hs  = (const float*)d_in[0];
    const int*   pos = (const int*)d_in[1];
    const float* wq  = (const float*)d_in[2];
    const float* wk  = (const float*)d_in[3];
    const float* wv  = (const float*)d_in[4];
    const float* wo  = (const float*)d_in[5];
    float* out = (float*)d_out;

    char* ws = (char*)d_ws;
    float*          Qb    = (float*)(ws);                        // 64 MB [4096,4096] fp32 (Q, then O)
    float*          Kb    = (float*)(ws + ((size_t)64  << 20));  // 16 MB [4096,1024] fp32
    float*          Vb    = (float*)(ws + ((size_t)80  << 20));  // 16 MB
    float*          cosT  = (float*)(ws + ((size_t)96  << 20));  // 512 KB
    float*          sinT  = (float*)(ws + ((size_t)96  << 20) + (size_t)SLEN * 64 * 4);
    unsigned short* hs_bf = (unsigned short*)(ws + ((size_t)97  << 20));  // 32 MB (hs_bf, then O_bf)
    unsigned short* wqo_bf= (unsigned short*)(ws + ((size_t)129 << 20));  // 32 MB (wq_bf, then wo_bf)
    unsigned short* wk_bf = (unsigned short*)(ws + ((size_t)161 << 20));  // 8 MB
    unsigned short* wv_bf = (unsigned short*)(ws + ((size_t)169 << 20));  // 8 MB
    // total 177 MB

    const long nHS = (long)MROWS * DMODEL;        // 16M
    const long nWQ = (long)DMODEL * DMODEL;       // 16M
    const long nWK = (long)KVDIM * DMODEL;        // 4M

    rope_table_k<<<SLEN, 64, 0, stream>>>(pos, cosT, sinT);

    cast_k<<<nHS / 4 / 256, 256, 0, stream>>>(hs, hs_bf, nHS);
    cast_k<<<nWQ / 4 / 256, 256, 0, stream>>>(wq, wqo_bf, nWQ);
    cast_k<<<nWK / 4 / 256, 256, 0, stream>>>(wk, wk_bf, nWK);
    cast_k<<<nWK / 4 / 256, 256, 0, stream>>>(wv, wv_bf, nWK);

    dim3 blk(256);
    gemm_bf16_nt<<<dim3(DMODEL/128, MROWS/128), blk, 0, stream>>>(hs_bf, wqo_bf, Qb, MROWS, DMODEL, DMODEL);
    // wq no longer needed: reuse its slot for wo
    cast_k<<<nWQ / 4 / 256, 256, 0, stream>>>(wo, wqo_bf, nWQ);
    gemm_bf16_nt<<<dim3(KVDIM/128,  MROWS/128), blk, 0, stream>>>(hs_bf, wk_bf, Kb, MROWS, KVDIM, DMODEL);
    gemm_bf16_nt<<<dim3(KVDIM/128,  MROWS/128), blk, 0, stream>>>(hs_bf, wv_bf, Vb, MROWS, KVDIM, DMODEL);

    rope_apply_k<<<(MROWS * NHEADS  * 64) / 256, 256, 0, stream>>>(Qb, cosT, sinT, NHEADS);
    rope_apply_k<<<(MROWS * KVHEADS * 64) / 256, 256, 0, stream>>>(Kb, cosT, sinT, KVHEADS);

    flash_k<<<dim3(SLEN/64, BATCH*NHEADS), blk, 0, stream>>>(Qb, Kb, Vb, Qb);

    // O (fp32, in Qb) -> bf16 into hs_bf slot
    cast_k<<<nHS / 4 / 256, 256, 0, stream>>>(Qb, hs_bf, nHS);
    gemm_bf16_nt<<<dim3(DMODEL/128, MROWS/128), blk, 0, stream>>>(hs_bf, wqo_bf, out, MROWS, DMODEL, DMODEL);
}

// Round 3
// 944.088 us; speedup vs baseline: 10.1236x; 3.8838x over previous
//
#include <hip/hip_runtime.h>
#include <hip/hip_bf16.h>
#include <math.h>

typedef __attribute__((ext_vector_type(8))) short short8;
typedef __attribute__((ext_vector_type(4))) float f32x4;

#define BATCH   2
#define SLEN    2048
#define DMODEL  4096
#define NHEADS  32
#define KVHEADS 8
#define HD      128
#define KVDIM   (KVHEADS*HD)   // 1024
#define MROWS   (BATCH*SLEN)   // 4096

// async global->LDS, 16B per lane, dest = wave-uniform base + lane*16
#define GLDS16(gp, lp) __builtin_amdgcn_global_load_lds( \
    (const __attribute__((address_space(1))) void*)(gp), \
    (__attribute__((address_space(3))) void*)(lp), 16, 0, 0)

static __device__ __forceinline__ unsigned short bf16bits(float x) {
    __hip_bfloat16 h = __float2bfloat16(x);
    return *(unsigned short*)&h;
}

// ---------------- fp32 -> bf16 cast ----------------
__global__ __launch_bounds__(256) void cast_k(const float* __restrict__ in,
                                              unsigned short* __restrict__ out, long n) {
    long i = ((long)blockIdx.x * 256 + threadIdx.x) * 4;
    if (i >= n) return;
    float4 v = *(const float4*)(in + i);
    union { unsigned short h[4]; uint2 u; } c;
    c.h[0] = bf16bits(v.x); c.h[1] = bf16bits(v.y);
    c.h[2] = bf16bits(v.z); c.h[3] = bf16bits(v.w);
    *(uint2*)(out + i) = c.u;
}

// ---------------- RoPE tables ----------------
__global__ void rope_table_k(const int* __restrict__ pos,
                             float* __restrict__ cosT, float* __restrict__ sinT) {
    int s = blockIdx.x;
    int d = threadIdx.x;
    float p = (float)pos[s];
    float inv = powf(10000.0f, -(float)(2 * d) / 128.0f);
    float ang = p * inv;
    cosT[s * 64 + d] = cosf(ang);
    sinT[s * 64 + d] = sinf(ang);
}

// ---------------- RoPE apply + cast to bf16 ----------------
__global__ void rope_cast_k(const float* __restrict__ x, unsigned short* __restrict__ out,
                            const float* __restrict__ cosT, const float* __restrict__ sinT,
                            int nh) {
    int idx = blockIdx.x * 256 + threadIdx.x;
    int d = idx & 63;
    int rest = idx >> 6;
    int h = rest % nh;
    int row = rest / nh;
    int s = row & (SLEN - 1);
    float c  = cosT[s * 64 + d];
    float sn = sinT[s * 64 + d];
    const float* base = x + (size_t)row * (nh * HD) + h * HD;
    float x1 = base[d], x2 = base[d + 64];
    unsigned short* ob = out + (size_t)row * (nh * HD) + h * HD;
    ob[d]      = bf16bits(x1 * c - x2 * sn);
    ob[d + 64] = bf16bits(x2 * c + x1 * sn);
}

// ---------------- V transpose: fp32 [M][KVDIM] -> bf16 Vt[b*KVH+kvh][d=128][s=2048] ----------------
__global__ __launch_bounds__(256) void vtrans_k(const float* __restrict__ V,
                                                unsigned short* __restrict__ Vt) {
    __shared__ unsigned short L[64][144];   // pitch 288B: column stride 72 dwords -> no bank hot-spot
    const int t = threadIdx.x;
    const int s0 = blockIdx.x * 64;
    const int bk = blockIdx.y;              // b*KVH + kvh
    const int b = bk >> 3, kvh = bk & 7;
    {
        int sl = t >> 2;
        int d0 = (t & 3) * 32;
        const float* src = V + ((size_t)b * SLEN + s0 + sl) * KVDIM + kvh * HD + d0;
        unsigned short* dst = &L[sl][d0];
        #pragma unroll
        for (int j = 0; j < 8; ++j) {
            float4 v = *(const float4*)(src + j * 4);
            dst[j*4+0] = bf16bits(v.x); dst[j*4+1] = bf16bits(v.y);
            dst[j*4+2] = bf16bits(v.z); dst[j*4+3] = bf16bits(v.w);
        }
    }
    __syncthreads();
    {
        int d  = t >> 1;
        int sh = (t & 1) * 32;
        unsigned short tmp[32];
        #pragma unroll
        for (int j = 0; j < 32; ++j) tmp[j] = L[sh + j][d];
        unsigned short* dst = Vt + ((size_t)bk * HD + d) * SLEN + s0 + sh;
        #pragma unroll
        for (int j = 0; j < 4; ++j)
            *(short8*)(dst + j * 8) = *(const short8*)(tmp + j * 8);
    }
}

// ---------------- bf16 MFMA GEMM-NT (m97 structure, unchanged) ----------------
__global__ __launch_bounds__(256) void gemm_bf16_nt(
    const unsigned short* __restrict__ A,
    const unsigned short* __restrict__ W,
    float* __restrict__ C,
    int M, int N, int K)
{
    __shared__ unsigned short As[128 * 32];
    __shared__ unsigned short Bs[128 * 32];
    const int t    = threadIdx.x;
    const int wid  = t >> 6;
    const int lane = t & 63;
    const int m0 = blockIdx.y * 128, n0 = blockIdx.x * 128;
    const int wm = (wid >> 1) * 64, wn = (wid & 1) * 64;

    f32x4 acc[4][4];
    #pragma unroll
    for (int i = 0; i < 4; ++i)
        #pragma unroll
        for (int j = 0; j < 4; ++j)
            acc[i][j] = (f32x4){0.f, 0.f, 0.f, 0.f};

    const int srow  = wid * 16 + (lane >> 2);
    const int skcol = (lane & 3) * 8;
    const unsigned short* Abase = A + (size_t)(m0 + srow) * K + skcol;
    const unsigned short* Wbase = W + (size_t)(n0 + srow) * K + skcol;
    unsigned short* AsB = As + wid * 512;
    unsigned short* BsB = Bs + wid * 512;

    const int frow = lane & 15;
    const int fk   = (lane >> 4) * 8;

    for (int k0 = 0; k0 < K; k0 += 32) {
        __syncthreads();
        GLDS16(Abase + k0,                   AsB);
        GLDS16(Abase + (size_t)64 * K + k0,  AsB + 2048);
        GLDS16(Wbase + k0,                   BsB);
        GLDS16(Wbase + (size_t)64 * K + k0,  BsB + 2048);
        __syncthreads();

        short8 af[4], bfv[4];
        #pragma unroll
        for (int i = 0; i < 4; ++i)
            af[i] = *(const short8*)&As[(wm + i * 16 + frow) * 32 + fk];
        #pragma unroll
        for (int j = 0; j < 4; ++j)
            bfv[j] = *(const short8*)&Bs[(wn + j * 16 + frow) * 32 + fk];
        #pragma unroll
        for (int i = 0; i < 4; ++i)
            #pragma unroll
            for (int j = 0; j < 4; ++j)
                acc[i][j] = __builtin_amdgcn_mfma_f32_16x16x32_bf16(af[i], bfv[j], acc[i][j], 0, 0, 0);
    }

    const int crow = (lane >> 4) * 4, ccol = lane & 15;
    #pragma unroll
    for (int i = 0; i < 4; ++i)
        #pragma unroll
        for (int j = 0; j < 4; ++j) {
            float* cp = C + (size_t)(m0 + wm + i * 16 + crow) * N + (n0 + wn + j * 16 + ccol);
            #pragma unroll
            for (int r = 0; r < 4; ++r) cp[(size_t)r * N] = acc[i][j][r];
        }
}

// ---------------- MFMA flash attention, causal, GQA ----------------
// grid (32, 64); 4 waves; wave w owns Q rows q0+w*16..+15; KVBLK=64.
// Q/K LDS rows 256B, swizzle byte^=(row&15)<<4; Vt/P LDS rows 128B, swizzle (row&7)<<4.
__global__ __launch_bounds__(256) void flash_mfma(
    const unsigned short* __restrict__ Qb,   // [MROWS][DMODEL] bf16 (rope'd)
    const unsigned short* __restrict__ Kb,   // [MROWS][KVDIM] bf16 (rope'd)
    const unsigned short* __restrict__ Vt,   // [B*KVH][HD][SLEN] bf16
    unsigned short* __restrict__ Ob)         // [MROWS][DMODEL] bf16
{
    __shared__ unsigned short Qs[64 * 128];
    __shared__ unsigned short Ks[64 * 128];
    __shared__ unsigned short Vs[128 * 64];
    __shared__ unsigned short Ps[4][16 * 64];

    const int t = threadIdx.x;
    const int wid = t >> 6, lane = t & 63;
    const int qt = gridDim.x - 1 - blockIdx.x;    // heavy blocks first
    const int bh = blockIdx.y;
    const int b = bh >> 5, h = bh & 31, kvh = h >> 2;
    const int q0 = qt * 64;
    const size_t qrow = (size_t)b * SLEN + q0;
    const int fr = lane & 15;
    const int hi16 = (lane >> 4) << 4;            // 0,16,32,48 (byte slice base)

    // ---- stage Q tile once (pre-swizzled source, linear LDS dest)
    {
        const unsigned short* Qg = Qb + qrow * DMODEL + h * HD;
        #pragma unroll
        for (int i = 0; i < 4; ++i) {
            int row = i * 16 + (t >> 4);
            int colel = ((((t & 15) << 4) ^ ((row & 15) << 4)) >> 1);
            GLDS16(Qg + (size_t)row * DMODEL + colel, Qs + i * 2048 + wid * 512);
        }
    }
    __syncthreads();

    // ---- Q fragments to registers (Qs dead afterwards)
    short8 qf[4];
    {
        int row = wid * 16 + fr;
        const unsigned short* qp = Qs + row * 128;
        int sw = (row & 15) << 4;
        #pragma unroll
        for (int ks = 0; ks < 4; ++ks) {
            int pb = (ks * 64 + hi16) ^ sw;
            qf[ks] = *(const short8*)(qp + (pb >> 1));
        }
    }

    f32x4 accO[8];
    #pragma unroll
    for (int db = 0; db < 8; ++db) accO[db] = (f32x4){0.f, 0.f, 0.f, 0.f};
    float m_i[4] = {-INFINITY, -INFINITY, -INFINITY, -INFINITY};
    float l_i[4] = {0.f, 0.f, 0.f, 0.f};
    const float scale = 0.088388347648318447f;

    const unsigned short* Kg0 = Kb + (size_t)b * SLEN * KVDIM + kvh * HD;
    const unsigned short* Vg0 = Vt + (size_t)(b * KVHEADS + kvh) * HD * SLEN;

    for (int kt = 0; kt <= qt; ++kt) {
        __syncthreads();   // all waves done reading Ks/Vs of previous tile
        {
            const unsigned short* Kg = Kg0 + (size_t)kt * 64 * KVDIM;
            #pragma unroll
            for (int i = 0; i < 4; ++i) {
                int row = i * 16 + (t >> 4);
                int colel = ((((t & 15) << 4) ^ ((row & 15) << 4)) >> 1);
                GLDS16(Kg + (size_t)row * KVDIM + colel, Ks + i * 2048 + wid * 512);
            }
            const unsigned short* Vg = Vg0 + kt * 64;
            #pragma unroll
            for (int i = 0; i < 4; ++i) {
                int row = i * 32 + (t >> 3);
                int colel = ((((t & 7) << 4) ^ ((row & 7) << 4)) >> 1);
                GLDS16(Vg + (size_t)row * SLEN + colel, Vs + i * 2048 + wid * 512);
            }
        }
        __syncthreads();

        // ---- QK^T: 16 MFMA
        f32x4 sc[4];
        #pragma unroll
        for (int cb = 0; cb < 4; ++cb) {
            sc[cb] = (f32x4){0.f, 0.f, 0.f, 0.f};
            int krow = cb * 16 + fr;
            const unsigned short* kp = Ks + krow * 128;
            int sw = (krow & 15) << 4;
            #pragma unroll
            for (int ks = 0; ks < 4; ++ks) {
                int pb = (ks * 64 + hi16) ^ sw;
                short8 kf = *(const short8*)(kp + (pb >> 1));
                sc[cb] = __builtin_amdgcn_mfma_f32_16x16x32_bf16(qf[ks], kf, sc[cb], 0, 0, 0);
            }
        }

        // ---- mask + scale
        if (kt == qt) {
            #pragma unroll
            for (int cb = 0; cb < 4; ++cb)
                #pragma unroll
                for (int r = 0; r < 4; ++r) {
                    int kg = cb * 16 + fr;
                    int qg = wid * 16 + (lane >> 4) * 4 + r;
                    sc[cb][r] = (kg <= qg) ? sc[cb][r] * scale : -INFINITY;
                }
        } else {
            #pragma unroll
            for (int cb = 0; cb < 4; ++cb)
                #pragma unroll
                for (int r = 0; r < 4; ++r) sc[cb][r] *= scale;
        }

        // ---- online softmax (row reduce over 16 lanes)
        float pmax[4];
        #pragma unroll
        for (int r = 0; r < 4; ++r)
            pmax[r] = fmaxf(fmaxf(sc[0][r], sc[1][r]), fmaxf(sc[2][r], sc[3][r]));
        #pragma unroll
        for (int m = 1; m < 16; m <<= 1)
            #pragma unroll
            for (int r = 0; r < 4; ++r)
                pmax[r] = fmaxf(pmax[r], __shfl_xor(pmax[r], m));

        float alpha[4], rsum[4];
        #pragma unroll
        for (int r = 0; r < 4; ++r) {
            float mn = fmaxf(m_i[r], pmax[r]);
            alpha[r] = __expf(m_i[r] - mn);
            m_i[r] = mn;
            rsum[r] = 0.f;
        }
        #pragma unroll
        for (int cb = 0; cb < 4; ++cb)
            #pragma unroll
            for (int r = 0; r < 4; ++r) {
                float p = __expf(sc[cb][r] - m_i[r]);
                sc[cb][r] = p;
                rsum[r] += p;
            }
        #pragma unroll
        for (int m = 1; m < 16; m <<= 1)
            #pragma unroll
            for (int r = 0; r < 4; ++r)
                rsum[r] += __shfl_xor(rsum[r], m);
        #pragma unroll
        for (int r = 0; r < 4; ++r)
            l_i[r] = l_i[r] * alpha[r] + rsum[r];
        #pragma unroll
        for (int db = 0; db < 8; ++db)
            #pragma unroll
            for (int r = 0; r < 4; ++r)
                accO[db][r] *= alpha[r];

        // ---- P -> per-wave LDS (bf16, swizzled)
        {
            unsigned short* pw = Ps[wid];
            #pragma unroll
            for (int r = 0; r < 4; ++r) {
                int qr = (lane >> 4) * 4 + r;
                int sw = (qr & 7) << 4;
                #pragma unroll
                for (int cb = 0; cb < 4; ++cb) {
                    int pb = (cb * 32 + ((lane & 15) << 1)) ^ sw;
                    pw[qr * 64 + (pb >> 1)] = bf16bits(sc[cb][r]);
                }
            }
        }

        // ---- PV: 16 MFMA
        {
            const unsigned short* pr = Ps[wid];
            short8 pa[2];
            int swp = (fr & 7) << 4;
            #pragma unroll
            for (int ks = 0; ks < 2; ++ks) {
                int pb = (ks * 64 + hi16) ^ swp;
                pa[ks] = *(const short8*)(pr + fr * 64 + (pb >> 1));
            }
            #pragma unroll
            for (int db = 0; db < 8; ++db) {
                int vrow = db * 16 + fr;
                const unsigned short* vp = Vs + vrow * 64;
                int sw = (vrow & 7) << 4;
                #pragma unroll
                for (int ks = 0; ks < 2; ++ks) {
                    int pb = (ks * 64 + hi16) ^ sw;
                    short8 vf = *(const short8*)(vp + (pb >> 1));
                    accO[db] = __builtin_amdgcn_mfma_f32_16x16x32_bf16(pa[ks], vf, accO[db], 0, 0, 0);
                }
            }
        }
    }

    // ---- epilogue
    float inv[4];
    #pragma unroll
    for (int r = 0; r < 4; ++r) inv[r] = 1.0f / l_i[r];
    unsigned short* Og = Ob + (qrow + wid * 16 + (lane >> 4) * 4) * DMODEL + h * HD + fr;
    #pragma unroll
    for (int r = 0; r < 4; ++r)
        #pragma unroll
        for (int db = 0; db < 8; ++db)
            Og[(size_t)r * DMODEL + db * 16] = bf16bits(accO[db][r] * inv[r]);
}

extern "C" void kernel_launch(void* const* d_in, const int* in_sizes, int n_in,
                              void* d_out, int out_size, void* d_ws, size_t ws_size,
                              hipStream_t stream) {
    const float* hs  = (const float*)d_in[0];
    const int*   pos = (const int*)d_in[1];
    const float* wq  = (const float*)d_in[2];
    const float* wk  = (const float*)d_in[3];
    const float* wv  = (const float*)d_in[4];
    const float* wo  = (const float*)d_in[5];
    float* out = (float*)d_out;

    char* ws = (char*)d_ws;
    // region [0,64MB): Qb fp32 until rope_cast Q; then Obf(32MB)+Kbf(8MB)+Vt(8MB)
    float*          Qb    = (float*)(ws);
    unsigned short* Obf   = (unsigned short*)(ws);
    unsigned short* Kbf   = (unsigned short*)(ws + ((size_t)32  << 20));
    unsigned short* Vtb   = (unsigned short*)(ws + ((size_t)40  << 20));
    float*          KbF   = (float*)(ws + ((size_t)64  << 20));   // 16 MB fp32 K
    float*          VbF   = (float*)(ws + ((size_t)80  << 20));   // 16 MB fp32 V
    float*          cosT  = (float*)(ws + ((size_t)96  << 20));
    float*          sinT  = (float*)(ws + ((size_t)96  << 20) + (size_t)SLEN * 64 * 4);
    unsigned short* hs_bf = (unsigned short*)(ws + ((size_t)97  << 20));  // 32 MB; reused as Qbf
    unsigned short* Qbf   = hs_bf;
    unsigned short* wqo_bf= (unsigned short*)(ws + ((size_t)129 << 20));  // 32 MB (wq then wo)
    unsigned short* wk_bf = (unsigned short*)(ws + ((size_t)161 << 20));
    unsigned short* wv_bf = (unsigned short*)(ws + ((size_t)169 << 20));
    // total 177 MB

    const long nHS = (long)MROWS * DMODEL;
    const long nWQ = (long)DMODEL * DMODEL;
    const long nWK = (long)KVDIM * DMODEL;

    rope_table_k<<<SLEN, 64, 0, stream>>>(pos, cosT, sinT);

    cast_k<<<nHS / 4 / 256, 256, 0, stream>>>(hs, hs_bf, nHS);
    cast_k<<<nWQ / 4 / 256, 256, 0, stream>>>(wq, wqo_bf, nWQ);
    cast_k<<<nWK / 4 / 256, 256, 0, stream>>>(wk, wk_bf, nWK);
    cast_k<<<nWK / 4 / 256, 256, 0, stream>>>(wv, wv_bf, nWK);

    dim3 blk(256);
    gemm_bf16_nt<<<dim3(DMODEL/128, MROWS/128), blk, 0, stream>>>(hs_bf, wqo_bf, Qb, MROWS, DMODEL, DMODEL);
    cast_k<<<nWQ / 4 / 256, 256, 0, stream>>>(wo, wqo_bf, nWQ);
    gemm_bf16_nt<<<dim3(KVDIM/128,  MROWS/128), blk, 0, stream>>>(hs_bf, wk_bf, KbF, MROWS, KVDIM, DMODEL);
    gemm_bf16_nt<<<dim3(KVDIM/128,  MROWS/128), blk, 0, stream>>>(hs_bf, wv_bf, VbF, MROWS, KVDIM, DMODEL);

    // hs_bf dead -> its slot becomes Qbf
    rope_cast_k<<<(MROWS * NHEADS  * 64) / 256, 256, 0, stream>>>(Qb,  Qbf, cosT, sinT, NHEADS);
    // Qb (fp32) dead -> its region holds Obf/Kbf/Vt
    rope_cast_k<<<(MROWS * KVHEADS * 64) / 256, 256, 0, stream>>>(KbF, Kbf, cosT, sinT, KVHEADS);
    vtrans_k<<<dim3(SLEN/64, BATCH*KVHEADS), blk, 0, stream>>>(VbF, Vtb);

    flash_mfma<<<dim3(SLEN/64, BATCH*NHEADS), blk, 0, stream>>>(Qbf, Kbf, Vtb, Obf);

    gemm_bf16_nt<<<dim3(DMODEL/128, MROWS/128), blk, 0, stream>>>(Obf, wqo_bf, out, MROWS, DMODEL, DMODEL);
}